// Round 23
// baseline (1499.050 us; speedup 1.0000x reference)
//
#include <hip/hip_runtime.h>
#include <cstdint>
#include <cstddef>

#define NB_TOT 1024
#define NANT 64
#define MM 16
#define MPAD 17
#define DA 4096
#define MAXIT 20
#define SPB 2      // samples per block (loop kernel) -> 512 blocks -> 2 blocks/CU
#define NTHR 1024
#define JCOLS 4
#define L_CONST 10.0f
#define MD_BYTES ((size_t)NB_TOT * DA * sizeof(float))

// ========== Kernel A: md[b][a] = 1/||M_D column|| -> d_ws (round-19 form) ==========
__global__ __launch_bounds__(256, 8)
void md_kernel(const float* __restrict__ M_re, const float* __restrict__ M_im,
               const float* __restrict__ W_re, const float* __restrict__ W_im,
               float* __restrict__ md_ws)
{
  const int b   = blockIdx.x >> 1;
  const int h   = blockIdx.x & 1;
  const int tid = threadIdx.x;
  const float* MrS = M_re + (size_t)b*1024;
  const float* MiS = M_im + (size_t)b*1024;

  #pragma unroll
  for (int k = 0; k < 8; k++){
    const int col = h*2048 + k*256 + tid;
    float cr[MM], ci[MM];
    #pragma unroll
    for (int q = 0; q < MM; q++){ cr[q]=0.f; ci[q]=0.f; }
    #pragma unroll 2
    for (int n = 0; n < NANT; n++){
      float wr = W_re[(size_t)n*DA + col];
      float wi = W_im[(size_t)n*DA + col];
      const float* Mr = MrS + n*MM;
      const float* Mi = MiS + n*MM;
      #pragma unroll
      for (int q2 = 0; q2 < 4; q2++){
        float4 m4r = *(const float4*)(Mr + q2*4);
        float4 m4i = *(const float4*)(Mi + q2*4);
        cr[q2*4+0] += m4r.x*wr + m4i.x*wi;  ci[q2*4+0] += m4r.x*wi - m4i.x*wr;
        cr[q2*4+1] += m4r.y*wr + m4i.y*wi;  ci[q2*4+1] += m4r.y*wi - m4i.y*wr;
        cr[q2*4+2] += m4r.z*wr + m4i.z*wi;  ci[q2*4+2] += m4r.z*wi - m4i.z*wr;
        cr[q2*4+3] += m4r.w*wr + m4i.w*wi;  ci[q2*4+3] += m4r.w*wi - m4i.w*wr;
      }
    }
    float nrm = 0.f;
    #pragma unroll
    for (int q = 0; q < MM; q++) nrm += cr[q]*cr[q] + ci[q]*ci[q];
    md_ws[(size_t)b*DA + col] = 1.f/sqrtf(nrm);
  }
}

// ========== Kernel B: greedy loop, SPB=2 -> 512 blocks, 2 blocks/CU ==========
__global__ __launch_bounds__(NTHR, 4)
void loop_kernel(const float* __restrict__ x_re, const float* __restrict__ x_im,
                 const float* __restrict__ xm_re, const float* __restrict__ xm_im,
                 const float* __restrict__ M_re, const float* __restrict__ M_im,
                 const float* __restrict__ W_re, const float* __restrict__ W_im,
                 const float* __restrict__ sigma, const float* __restrict__ md_ws,
                 float* __restrict__ out, int outn_i)
{
  __shared__ float Msh_re[SPB][NANT][MPAD];   // 8.7 KB
  __shared__ float Msh_im[SPB][NANT][MPAD];   // 8.7 KB
  __shared__ float tsh[NANT][4];              // 1 KB: t0r,t0i,t1r,t1i
  __shared__ float rsd_re[SPB][MM], rsd_im[SPB][MM];
  __shared__ float resh_re[SPB][NANT], resh_im[SPB][NANT];
  __shared__ float red_c2[16][SPB];
  __shared__ int   red_ix[16][SPB];
  __shared__ float wselr[SPB][NANT], wseli[SPB][NANT];
  __shared__ int   sel_ix[SPB];
  __shared__ float sel_vr[SPB], sel_vi[SPB], sel_md[SPB], sel_ei[SPB];
  __shared__ float rn2_sh[SPB], thr_sh[SPB];
  __shared__ int   actsh[SPB];

  const int tid = threadIdx.x;
  const int b0 = blockIdx.x * SPB;
  const size_t outn = (size_t)outn_i;

  // ---- init: stage M (2048 elems, 2 passes), residual, res, thresholds
  for (int k2 = 0; k2 < 2; k2++){
    int idx = k2*NTHR + tid;            // 0..2047 = 2 samples x 64 n x 16 m
    int s = idx >> 10, rem = idx & 1023;
    int n = rem >> 4, m = rem & 15;
    Msh_re[s][n][m] = M_re[(size_t)b0*1024 + idx];
    Msh_im[s][n][m] = M_im[(size_t)b0*1024 + idx];
  }
  if (tid < SPB*MM){
    int s = tid >> 4, m = tid & 15;
    rsd_re[s][m] = x_re[(b0+s)*MM + m];
    rsd_im[s][m] = x_im[(b0+s)*MM + m];
  } else if (tid >= 64 && tid < 64 + SPB*NANT){
    int q = tid - 64, s = q >> 6, n = q & 63;
    resh_re[s][n] = xm_re[(b0+s)*NANT + n];
    resh_im[s][n] = xm_im[(b0+s)*NANT + n];
  } else if (tid >= 448 && tid < 448 + SPB){
    int s = tid - 448;
    float sg = sigma[b0+s];
    thr_sh[s] = ((sg*sg) * (float)NANT) * L_CONST;
    actsh[s] = 1;
  }
  __syncthreads();

  for (int it = 0; it < MAXIT; it++){
    // A: rn2 (tid<2), t = M.residual for active samples (tid 64..191)
    if (tid < SPB){
      float e = 0.f;
      #pragma unroll
      for (int m = 0; m < MM; m++){
        float rr = rsd_re[tid][m], ri = rsd_im[tid][m];
        e += rr*rr + ri*ri;
      }
      rn2_sh[tid] = e;
    } else if (tid >= 64 && tid < 64 + SPB*NANT){
      int q = tid - 64, s = q >> 6, n = q & 63;
      if (actsh[s]){
        float tr = 0.f, ti = 0.f;
        #pragma unroll
        for (int m = 0; m < MM; m++){
          float mr = Msh_re[s][n][m], mi = Msh_im[s][n][m];
          float rr = rsd_re[s][m], ri = rsd_im[s][m];
          tr += mr*rr - mi*ri;
          ti += mr*ri + mi*rr;
        }
        tsh[n][2*s]   = tr;
        tsh[n][2*s+1] = ti;
      }
    }
    __syncthreads();

    bool a0 = actsh[0] && (rn2_sh[0] >= thr_sh[0]);
    bool a1 = actsh[1] && (rn2_sh[1] >= thr_sh[1]);
    if (tid < SPB){
      int v = (tid==0) ? (int)a0 : (int)a1;
      actsh[tid] = v;
    }
    if (!(a0 || a1)) break;

    // B: g[s][j] = sum_n conj(W[n,a])*t[s,n], a = tid*4+j ; gated per sample
    float gr[SPB][JCOLS], gi[SPB][JCOLS];
    #pragma unroll
    for (int s = 0; s < SPB; s++)
      #pragma unroll
      for (int j = 0; j < JCOLS; j++){ gr[s][j]=0.f; gi[s][j]=0.f; }
    #pragma unroll 8
    for (int n = 0; n < NANT; n++){
      float4 t01 = *(const float4*)&tsh[n][0];     // t0r,t0i,t1r,t1i
      float4 wr = *(const float4*)(W_re + (size_t)n*DA + (tid<<2));
      float4 wi = *(const float4*)(W_im + (size_t)n*DA + (tid<<2));
      if (a0){
        gr[0][0] += wr.x*t01.x + wi.x*t01.y;  gi[0][0] += wr.x*t01.y - wi.x*t01.x;
        gr[0][1] += wr.y*t01.x + wi.y*t01.y;  gi[0][1] += wr.y*t01.y - wi.y*t01.x;
        gr[0][2] += wr.z*t01.x + wi.z*t01.y;  gi[0][2] += wr.z*t01.y - wi.z*t01.x;
        gr[0][3] += wr.w*t01.x + wi.w*t01.y;  gi[0][3] += wr.w*t01.y - wi.w*t01.x;
      }
      if (a1){
        gr[1][0] += wr.x*t01.z + wi.x*t01.w;  gi[1][0] += wr.x*t01.w - wi.x*t01.z;
        gr[1][1] += wr.y*t01.z + wi.y*t01.w;  gi[1][1] += wr.y*t01.w - wi.y*t01.z;
        gr[1][2] += wr.z*t01.z + wi.z*t01.w;  gi[1][2] += wr.z*t01.w - wi.z*t01.z;
        gr[1][3] += wr.w*t01.z + wi.w*t01.w;  gi[1][3] += wr.w*t01.w - wi.w*t01.z;
      }
    }

    // C: per-thread best; md direct (L3/L2), then wave reduce
    const bool acts[SPB] = {a0, a1};
    float bc2[SPB]; int bix[SPB];
    #pragma unroll
    for (int s = 0; s < SPB; s++){
      bc2[s] = -1.f; bix[s] = 0;
      if (acts[s]){
        float4 md4 = *(const float4*)(md_ws + (size_t)(b0+s)*DA + (tid<<2));
        float c0 = (gr[s][0]*gr[s][0] + gi[s][0]*gi[s][0]) * (md4.x*md4.x);
        float c1 = (gr[s][1]*gr[s][1] + gi[s][1]*gi[s][1]) * (md4.y*md4.y);
        float c2v = (gr[s][2]*gr[s][2] + gi[s][2]*gi[s][2]) * (md4.z*md4.z);
        float c3 = (gr[s][3]*gr[s][3] + gi[s][3]*gi[s][3]) * (md4.w*md4.w);
        float bc = c0; int bi = (tid<<2);
        if (c1 > bc){ bc = c1; bi = (tid<<2)+1; }
        if (c2v > bc){ bc = c2v; bi = (tid<<2)+2; }
        if (c3 > bc){ bc = c3; bi = (tid<<2)+3; }
        bc2[s] = bc; bix[s] = bi;
      }
    }
    #pragma unroll
    for (int s = 0; s < SPB; s++){
      if (acts[s]){
        #pragma unroll
        for (int off = 32; off; off >>= 1){
          float oc2 = __shfl_down(bc2[s], off);
          int   oix = __shfl_down(bix[s], off);
          if (oc2 > bc2[s] || (oc2 == bc2[s] && oix < bix[s])){ bc2[s]=oc2; bix[s]=oix; }
        }
      }
    }
    if ((tid & 63) == 0){
      int wid = tid >> 6;
      #pragma unroll
      for (int s = 0; s < SPB; s++){
        if (acts[s]){ red_c2[wid][s]=bc2[s]; red_ix[wid][s]=bix[s]; }
      }
    }
    __syncthreads();

    // D1 (wave s, lane=n): cross-wave argmax; val, w2; stage W[:,I] to LDS
    if (tid < SPB*64){
      int s = tid >> 6, lane = tid & 63;
      if (actsh[s]){
        float c = (lane < 16) ? red_c2[lane][s] : -1.f;
        int   bi = (lane < 16) ? red_ix[lane][s] : 0x7FFFFFFF;
        #pragma unroll
        for (int off = 8; off; off >>= 1){
          float oc = __shfl_xor(c, off, 16);
          int   oi = __shfl_xor(bi, off, 16);
          if (oc > c || (oc == c && oi < bi)){ c = oc; bi = oi; }
        }
        int I = __shfl(bi, 0);
        float wr = W_re[(size_t)lane*DA + I], wi = W_im[(size_t)lane*DA + I];
        wselr[s][lane] = wr;
        wseli[s][lane] = wi;
        float tr = tsh[lane][2*s], ti = tsh[lane][2*s+1];
        float vr = wr*tr + wi*ti;
        float vi = wr*ti - wi*tr;
        float w2 = wr*wr + wi*wi;
        #pragma unroll
        for (int off = 32; off; off >>= 1){
          vr += __shfl_xor(vr, off);
          vi += __shfl_xor(vi, off);
          w2 += __shfl_xor(w2, off);
        }
        if (lane == 0){
          float mdv = md_ws[(size_t)(b0+s)*DA + I];
          sel_ix[s] = I;
          sel_vr[s] = vr*mdv;
          sel_vi[s] = vi*mdv;
          sel_md[s] = mdv;
          sel_ei[s] = rsqrtf(w2);
        }
      }
    }
    __syncthreads();

    // D2 (block-parallel): tid<256 -> col[s][m] dots + rsd update;
    //                      256..383 -> res update from staged W
    if (tid < SPB*128){
      int s = tid >> 7, rem = tid & 127, m = rem >> 3, g = rem & 7;
      if (actsh[s]){
        float pr = 0.f, pi = 0.f;
        #pragma unroll
        for (int j = 0; j < 8; j++){
          int n = g*8 + j;
          float mr = Msh_re[s][n][m], mi = Msh_im[s][n][m];
          float wr = wselr[s][n],     wi = wseli[s][n];
          pr += mr*wr + mi*wi;
          pi += mr*wi - mi*wr;
        }
        pr += __shfl_xor(pr, 4, 8);  pi += __shfl_xor(pi, 4, 8);
        pr += __shfl_xor(pr, 2, 8);  pi += __shfl_xor(pi, 2, 8);
        pr += __shfl_xor(pr, 1, 8);  pi += __shfl_xor(pi, 1, 8);
        if (g == 0){
          float mdv = sel_md[s], vr = sel_vr[s], vi = sel_vi[s];
          float cr = pr*mdv, ci2 = pi*mdv;
          rsd_re[s][m] -= vr*cr - vi*ci2;
          rsd_im[s][m] -= vr*ci2 + vi*cr;
        }
      }
    } else if (tid < SPB*128 + SPB*64){
      int q = tid - SPB*128, s = q >> 6, n = q & 63;
      if (actsh[s]){
        float wr = wselr[s][n], wi = wseli[s][n];
        float ei = sel_ei[s], vr = sel_vr[s], vi = sel_vi[s];
        float er = wr*ei, em = wi*ei;
        resh_re[s][n] -= vr*er - vi*em;
        resh_im[s][n] -= vr*em + vi*er;
      }
    }
    __syncthreads();
  }

  // ---- epilogue: f32, six planes (re: res,xhat,xhm then im: res,xhat,xhm)
  if (tid < SPB*MM){
    int s = tid >> 4, m = tid & 15; int b = b0 + s;
    float rr = rsd_re[s][m], ri = rsd_im[s][m];
    size_t base = (size_t)b*MM + m;
    if (base < outn)          out[base]          = rr;
    if (16384 + base < outn)  out[16384 + base]  = x_re[b*MM+m] - rr;
    if (98304 + base < outn)  out[98304 + base]  = ri;
    if (114688 + base < outn) out[114688 + base] = x_im[b*MM+m] - ri;
  } else if (tid >= 64 && tid < 64 + SPB*NANT){
    int q = tid - 64, s = q >> 6, n = q & 63; int b = b0 + s;
    size_t base = (size_t)b*NANT + n;
    if (32768 + base < outn)  out[32768 + base]  = xm_re[b*NANT+n] - resh_re[s][n];
    if (131072 + base < outn) out[131072 + base] = xm_im[b*NANT+n] - resh_im[s][n];
  }
}

// ================= Fallback: fused single-kernel path (SPB=4 form) ================
#define FSPB 4
__global__ __launch_bounds__(NTHR, 4)
void fused_kernel(const float* __restrict__ x_re, const float* __restrict__ x_im,
                  const float* __restrict__ xm_re, const float* __restrict__ xm_im,
                  const float* __restrict__ M_re, const float* __restrict__ M_im,
                  const float* __restrict__ W_re, const float* __restrict__ W_im,
                  const float* __restrict__ sigma,
                  float* __restrict__ out, int outn_i)
{
  __shared__ float Msh_re[FSPB][NANT][MPAD];
  __shared__ float Msh_im[FSPB][NANT][MPAD];
  __shared__ float md_T[FSPB][JCOLS][NTHR];
  __shared__ float tsh[NANT][8];
  __shared__ float rsd_re[FSPB][MM], rsd_im[FSPB][MM];
  __shared__ float resh_re[FSPB][NANT], resh_im[FSPB][NANT];
  __shared__ float red_c2[16][FSPB];
  __shared__ int   red_ix[16][FSPB];
  __shared__ float rn2_sh[FSPB], thr_sh[FSPB];
  __shared__ int   actsh[FSPB];

  const int tid = threadIdx.x;
  const int b0 = blockIdx.x * FSPB;
  const size_t outn = (size_t)outn_i;

  for (int k2 = 0; k2 < 4; k2++){
    int idx = k2*NTHR + tid;
    int s = idx >> 10, rem = idx & 1023;
    int n = rem >> 4, m = rem & 15;
    Msh_re[s][n][m] = M_re[(size_t)b0*1024 + idx];
    Msh_im[s][n][m] = M_im[(size_t)b0*1024 + idx];
  }
  if (tid < FSPB*MM){
    int s = tid >> 4, m = tid & 15;
    rsd_re[s][m] = x_re[(b0+s)*MM + m];
    rsd_im[s][m] = x_im[(b0+s)*MM + m];
  } else if (tid >= 64 && tid < 64 + FSPB*NANT){
    int q = tid - 64, s = q >> 6, n = q & 63;
    resh_re[s][n] = xm_re[(b0+s)*NANT + n];
    resh_im[s][n] = xm_im[(b0+s)*NANT + n];
  } else if (tid >= 448 && tid < 448 + FSPB){
    int s = tid - 448;
    float sg = sigma[b0+s];
    thr_sh[s] = ((sg*sg) * (float)NANT) * L_CONST;
    actsh[s] = 1;
  }

  #pragma unroll
  for (int s = 0; s < FSPB; s++){
    const float* MrS = M_re + (size_t)(b0+s)*1024;
    const float* MiS = M_im + (size_t)(b0+s)*1024;
    #pragma unroll
    for (int jc = 0; jc < JCOLS; jc++){
      const int col = (tid<<2) + jc;
      float cr[MM], ci[MM];
      #pragma unroll
      for (int q = 0; q < MM; q++){ cr[q]=0.f; ci[q]=0.f; }
      #pragma unroll 2
      for (int n = 0; n < NANT; n++){
        float wr = W_re[(size_t)n*DA + col];
        float wi = W_im[(size_t)n*DA + col];
        const float* Mr = MrS + n*MM;
        const float* Mi = MiS + n*MM;
        #pragma unroll
        for (int q2 = 0; q2 < 4; q2++){
          float4 m4r = *(const float4*)(Mr + q2*4);
          float4 m4i = *(const float4*)(Mi + q2*4);
          cr[q2*4+0] += m4r.x*wr + m4i.x*wi;  ci[q2*4+0] += m4r.x*wi - m4i.x*wr;
          cr[q2*4+1] += m4r.y*wr + m4i.y*wi;  ci[q2*4+1] += m4r.y*wi - m4i.y*wr;
          cr[q2*4+2] += m4r.z*wr + m4i.z*wi;  ci[q2*4+2] += m4r.z*wi - m4i.z*wr;
          cr[q2*4+3] += m4r.w*wr + m4i.w*wi;  ci[q2*4+3] += m4r.w*wi - m4i.w*wr;
        }
      }
      float nrm = 0.f;
      #pragma unroll
      for (int q = 0; q < MM; q++) nrm += cr[q]*cr[q] + ci[q]*ci[q];
      md_T[s][jc][tid] = 1.f/sqrtf(nrm);
    }
  }
  __syncthreads();

  for (int it = 0; it < MAXIT; it++){
    if (tid < FSPB){
      float e = 0.f;
      #pragma unroll
      for (int m = 0; m < MM; m++){
        float rr = rsd_re[tid][m], ri = rsd_im[tid][m];
        e += rr*rr + ri*ri;
      }
      rn2_sh[tid] = e;
    } else if (tid >= 64 && tid < 320){
      int q = tid - 64, s = q >> 6, n = q & 63;
      if (actsh[s]){
        float tr = 0.f, ti = 0.f;
        #pragma unroll
        for (int m = 0; m < MM; m++){
          float mr = Msh_re[s][n][m], mi = Msh_im[s][n][m];
          float rr = rsd_re[s][m], ri = rsd_im[s][m];
          tr += mr*rr - mi*ri;
          ti += mr*ri + mi*rr;
        }
        tsh[n][2*s]   = tr;
        tsh[n][2*s+1] = ti;
      }
    }
    __syncthreads();

    bool a0 = actsh[0] && (rn2_sh[0] >= thr_sh[0]);
    bool a1 = actsh[1] && (rn2_sh[1] >= thr_sh[1]);
    bool a2 = actsh[2] && (rn2_sh[2] >= thr_sh[2]);
    bool a3 = actsh[3] && (rn2_sh[3] >= thr_sh[3]);
    if (tid < 4){
      int v = (tid==0) ? (int)a0 : (tid==1) ? (int)a1 : (tid==2) ? (int)a2 : (int)a3;
      actsh[tid] = v;
    }
    if (!(a0 || a1 || a2 || a3)) break;

    float gr[FSPB][JCOLS], gi[FSPB][JCOLS];
    #pragma unroll
    for (int s = 0; s < FSPB; s++)
      #pragma unroll
      for (int j = 0; j < JCOLS; j++){ gr[s][j]=0.f; gi[s][j]=0.f; }
    #pragma unroll 8
    for (int n = 0; n < NANT; n++){
      float4 t01 = *(const float4*)&tsh[n][0];
      float4 t23 = *(const float4*)&tsh[n][4];
      float4 wr = *(const float4*)(W_re + (size_t)n*DA + (tid<<2));
      float4 wi = *(const float4*)(W_im + (size_t)n*DA + (tid<<2));
      if (a0){
        gr[0][0] += wr.x*t01.x + wi.x*t01.y;  gi[0][0] += wr.x*t01.y - wi.x*t01.x;
        gr[0][1] += wr.y*t01.x + wi.y*t01.y;  gi[0][1] += wr.y*t01.y - wi.y*t01.x;
        gr[0][2] += wr.z*t01.x + wi.z*t01.y;  gi[0][2] += wr.z*t01.y - wi.z*t01.x;
        gr[0][3] += wr.w*t01.x + wi.w*t01.y;  gi[0][3] += wr.w*t01.y - wi.w*t01.x;
      }
      if (a1){
        gr[1][0] += wr.x*t01.z + wi.x*t01.w;  gi[1][0] += wr.x*t01.w - wi.x*t01.z;
        gr[1][1] += wr.y*t01.z + wi.y*t01.w;  gi[1][1] += wr.y*t01.w - wi.y*t01.z;
        gr[1][2] += wr.z*t01.z + wi.z*t01.w;  gi[1][2] += wr.z*t01.w - wi.z*t01.z;
        gr[1][3] += wr.w*t01.z + wi.w*t01.w;  gi[1][3] += wr.w*t01.w - wi.w*t01.z;
      }
      if (a2){
        gr[2][0] += wr.x*t23.x + wi.x*t23.y;  gi[2][0] += wr.x*t23.y - wi.x*t23.x;
        gr[2][1] += wr.y*t23.x + wi.y*t23.y;  gi[2][1] += wr.y*t23.y - wi.y*t23.x;
        gr[2][2] += wr.z*t23.x + wi.z*t23.y;  gi[2][2] += wr.z*t23.y - wi.z*t23.x;
        gr[2][3] += wr.w*t23.x + wi.w*t23.y;  gi[2][3] += wr.w*t23.y - wi.w*t23.x;
      }
      if (a3){
        gr[3][0] += wr.x*t23.z + wi.x*t23.w;  gi[3][0] += wr.x*t23.w - wi.x*t23.z;
        gr[3][1] += wr.y*t23.z + wi.y*t23.w;  gi[3][1] += wr.y*t23.w - wi.y*t23.z;
        gr[3][2] += wr.z*t23.z + wi.z*t23.w;  gi[3][2] += wr.z*t23.w - wi.z*t23.z;
        gr[3][3] += wr.w*t23.z + wi.w*t23.w;  gi[3][3] += wr.w*t23.w - wi.w*t23.z;
      }
    }

    const bool acts[4] = {a0, a1, a2, a3};
    float bc2[FSPB]; int bix[FSPB];
    #pragma unroll
    for (int s = 0; s < FSPB; s++){
      bc2[s] = -1.f; bix[s] = 0;
      if (acts[s]){
        float m0 = md_T[s][0][tid], m1 = md_T[s][1][tid];
        float m2 = md_T[s][2][tid], m3 = md_T[s][3][tid];
        float c0 = (gr[s][0]*gr[s][0] + gi[s][0]*gi[s][0]) * (m0*m0);
        float c1 = (gr[s][1]*gr[s][1] + gi[s][1]*gi[s][1]) * (m1*m1);
        float c2v = (gr[s][2]*gr[s][2] + gi[s][2]*gi[s][2]) * (m2*m2);
        float c3 = (gr[s][3]*gr[s][3] + gi[s][3]*gi[s][3]) * (m3*m3);
        float bc = c0; int bi = (tid<<2);
        if (c1 > bc){ bc = c1; bi = (tid<<2)+1; }
        if (c2v > bc){ bc = c2v; bi = (tid<<2)+2; }
        if (c3 > bc){ bc = c3; bi = (tid<<2)+3; }
        bc2[s] = bc; bix[s] = bi;
      }
    }
    #pragma unroll
    for (int s = 0; s < FSPB; s++){
      if (acts[s]){
        #pragma unroll
        for (int off = 32; off; off >>= 1){
          float oc2 = __shfl_down(bc2[s], off);
          int   oix = __shfl_down(bix[s], off);
          if (oc2 > bc2[s] || (oc2 == bc2[s] && oix < bix[s])){ bc2[s]=oc2; bix[s]=oix; }
        }
      }
    }
    if ((tid & 63) == 0){
      int wid = tid >> 6;
      #pragma unroll
      for (int s = 0; s < FSPB; s++){
        if (acts[s]){ red_c2[wid][s]=bc2[s]; red_ix[wid][s]=bix[s]; }
      }
    }
    __syncthreads();

    if (tid < 256){
      int s = tid >> 6, lane = tid & 63;
      if (actsh[s]){
        float c = (lane < 16) ? red_c2[lane][s] : -1.f;
        int   bi = (lane < 16) ? red_ix[lane][s] : 0x7FFFFFFF;
        #pragma unroll
        for (int off = 8; off; off >>= 1){
          float oc = __shfl_xor(c, off);
          int   oi = __shfl_xor(bi, off);
          if (oc > c || (oc == c && oi < bi)){ c = oc; bi = oi; }
        }
        int I = __shfl(bi, 0);
        float wr = W_re[(size_t)lane*DA + I], wi = W_im[(size_t)lane*DA + I];
        float tr = tsh[lane][2*s], ti = tsh[lane][2*s+1];
        float vr = wr*tr + wi*ti;
        float vi = wr*ti - wi*tr;
        float w2 = wr*wr + wi*wi;
        #pragma unroll
        for (int off = 32; off; off >>= 1){
          vr += __shfl_xor(vr, off);
          vi += __shfl_xor(vi, off);
          w2 += __shfl_xor(w2, off);
        }
        float mdv = md_T[s][I & 3][I >> 2];
        float val_r = vr*mdv, val_i = vi*mdv;
        float einv = rsqrtf(w2);
        float er = wr*einv, em = wi*einv;
        resh_re[s][lane] -= val_r*er - val_i*em;
        resh_im[s][lane] -= val_r*em + val_i*er;
        for (int m = 0; m < MM; m++){
          float mr = Msh_re[s][lane][m], mi = Msh_im[s][lane][m];
          float pr = mr*wr + mi*wi;
          float pi = mr*wi - mi*wr;
          #pragma unroll
          for (int off = 32; off; off >>= 1){
            pr += __shfl_xor(pr, off);
            pi += __shfl_xor(pi, off);
          }
          if (lane == m){
            float col_r = pr*mdv, col_i = pi*mdv;
            rsd_re[s][m] -= val_r*col_r - val_i*col_i;
            rsd_im[s][m] -= val_r*col_i + val_i*col_r;
          }
        }
      }
    }
    __syncthreads();
  }

  if (tid < FSPB*MM){
    int s = tid >> 4, m = tid & 15; int b = b0 + s;
    float rr = rsd_re[s][m], ri = rsd_im[s][m];
    size_t base = (size_t)b*MM + m;
    if (base < outn)          out[base]          = rr;
    if (16384 + base < outn)  out[16384 + base]  = x_re[b*MM+m] - rr;
    if (98304 + base < outn)  out[98304 + base]  = ri;
    if (114688 + base < outn) out[114688 + base] = x_im[b*MM+m] - ri;
  } else if (tid >= 64 && tid < 64 + FSPB*NANT){
    int q = tid - 64, s = q >> 6, n = q & 63; int b = b0 + s;
    size_t base = (size_t)b*NANT + n;
    if (32768 + base < outn)  out[32768 + base]  = xm_re[b*NANT+n] - resh_re[s][n];
    if (131072 + base < outn) out[131072 + base] = xm_im[b*NANT+n] - resh_im[s][n];
  }
}

extern "C" void kernel_launch(void* const* d_in, const int* in_sizes, int n_in,
                              void* d_out, int out_size, void* d_ws, size_t ws_size,
                              hipStream_t stream) {
  (void)in_sizes; (void)n_in;
  const float* x_re  = (const float*)d_in[0];
  const float* x_im  = (const float*)d_in[1];
  const float* xm_re = (const float*)d_in[2];
  const float* xm_im = (const float*)d_in[3];
  const float* M_re  = (const float*)d_in[4];
  const float* M_im  = (const float*)d_in[5];
  const float* W_re  = (const float*)d_in[6];
  const float* W_im  = (const float*)d_in[7];
  const float* sig   = (const float*)d_in[8];
  float* out = (float*)d_out;

  if (ws_size >= MD_BYTES && d_ws != nullptr){
    float* md_ws = (float*)d_ws;
    hipLaunchKernelGGL(md_kernel, dim3(2048), dim3(256), 0, stream,
                       M_re, M_im, W_re, W_im, md_ws);
    hipLaunchKernelGGL(loop_kernel, dim3(NB_TOT / SPB), dim3(NTHR), 0, stream,
                       x_re, x_im, xm_re, xm_im, M_re, M_im, W_re, W_im,
                       sig, md_ws, out, out_size);
  } else {
    hipLaunchKernelGGL(fused_kernel, dim3(NB_TOT / FSPB), dim3(NTHR), 0, stream,
                       x_re, x_im, xm_re, xm_im, M_re, M_im, W_re, W_im,
                       sig, out, out_size);
  }
}

// Round 24
// 1338.454 us; speedup vs baseline: 1.1200x; 1.1200x over previous
//
#include <hip/hip_runtime.h>
#include <cstdint>
#include <cstddef>

#define NB_TOT 1024
#define NANT 64
#define MM 16
#define MPAD 17
#define DA 4096
#define MAXIT 20
#define SPB 4
#define NTHR 1024
#define JCOLS 4
#define L_CONST 10.0f
#define MD_BYTES ((size_t)NB_TOT * DA * sizeof(float))

// ========== Kernel A: md[b][a] = 1/||M_D column|| -> d_ws ==========
__global__ __launch_bounds__(256, 8)
void md_kernel(const float* __restrict__ M_re, const float* __restrict__ M_im,
               const float* __restrict__ W_re, const float* __restrict__ W_im,
               float* __restrict__ md_ws)
{
  const int b   = blockIdx.x >> 1;
  const int h   = blockIdx.x & 1;
  const int tid = threadIdx.x;
  const float* MrS = M_re + (size_t)b*1024;
  const float* MiS = M_im + (size_t)b*1024;

  #pragma unroll
  for (int k = 0; k < 8; k++){
    const int col = h*2048 + k*256 + tid;
    float cr[MM], ci[MM];
    #pragma unroll
    for (int q = 0; q < MM; q++){ cr[q]=0.f; ci[q]=0.f; }
    #pragma unroll 4
    for (int n = 0; n < NANT; n++){
      float wr = W_re[(size_t)n*DA + col];
      float wi = W_im[(size_t)n*DA + col];
      const float* Mr = MrS + n*MM;
      const float* Mi = MiS + n*MM;
      #pragma unroll
      for (int q2 = 0; q2 < 4; q2++){
        float4 m4r = *(const float4*)(Mr + q2*4);
        float4 m4i = *(const float4*)(Mi + q2*4);
        cr[q2*4+0] += m4r.x*wr + m4i.x*wi;  ci[q2*4+0] += m4r.x*wi - m4i.x*wr;
        cr[q2*4+1] += m4r.y*wr + m4i.y*wi;  ci[q2*4+1] += m4r.y*wi - m4i.y*wr;
        cr[q2*4+2] += m4r.z*wr + m4i.z*wi;  ci[q2*4+2] += m4r.z*wi - m4i.z*wr;
        cr[q2*4+3] += m4r.w*wr + m4i.w*wi;  ci[q2*4+3] += m4r.w*wi - m4i.w*wr;
      }
    }
    float nrm = 0.f;
    #pragma unroll
    for (int q = 0; q < MM; q++) nrm += cr[q]*cr[q] + ci[q]*ci[q];
    md_ws[(size_t)b*DA + col] = 1.f/sqrtf(nrm);
  }
}

// ========== Kernel B: greedy loop (round-21 structure + md in LDS) ==========
__global__ __launch_bounds__(NTHR, 4)
void loop_kernel(const float* __restrict__ x_re, const float* __restrict__ x_im,
                 const float* __restrict__ xm_re, const float* __restrict__ xm_im,
                 const float* __restrict__ M_re, const float* __restrict__ M_im,
                 const float* __restrict__ W_re, const float* __restrict__ W_im,
                 const float* __restrict__ sigma, const float* __restrict__ md_ws,
                 float* __restrict__ out, int outn_i)
{
  __shared__ float Msh_re[SPB][NANT][MPAD];    // 17.4 KB
  __shared__ float Msh_im[SPB][NANT][MPAD];    // 17.4 KB
  __shared__ float md_lds[SPB][JCOLS][NTHR];   // 64 KB, transposed lane-stride layout
  __shared__ float tsh[NANT][8];
  __shared__ float rsd_re[SPB][MM], rsd_im[SPB][MM];
  __shared__ float resh_re[SPB][NANT], resh_im[SPB][NANT];
  __shared__ float red_c2[16][SPB];
  __shared__ int   red_ix[16][SPB];
  __shared__ float wselr[SPB][NANT], wseli[SPB][NANT];
  __shared__ int   sel_ix[SPB];
  __shared__ float sel_vr[SPB], sel_vi[SPB], sel_md[SPB], sel_ei[SPB];
  __shared__ float rn2_sh[SPB], thr_sh[SPB];
  __shared__ int   actsh[SPB];

  const int tid = threadIdx.x;
  const int b0 = blockIdx.x * SPB;
  const size_t outn = (size_t)outn_i;

  // ---- init: stage M, residual(=x), res(=xm), thresholds
  for (int k2 = 0; k2 < 4; k2++){
    int idx = k2*NTHR + tid;
    int s = idx >> 10, rem = idx & 1023;
    int n = rem >> 4, m = rem & 15;
    Msh_re[s][n][m] = M_re[(size_t)b0*1024 + idx];
    Msh_im[s][n][m] = M_im[(size_t)b0*1024 + idx];
  }
  if (tid < SPB*MM){
    int s = tid >> 4, m = tid & 15;
    rsd_re[s][m] = x_re[(b0+s)*MM + m];
    rsd_im[s][m] = x_im[(b0+s)*MM + m];
  } else if (tid >= 64 && tid < 64 + SPB*NANT){
    int q = tid - 64, s = q >> 6, n = q & 63;
    resh_re[s][n] = xm_re[(b0+s)*NANT + n];
    resh_im[s][n] = xm_im[(b0+s)*NANT + n];
  } else if (tid >= 448 && tid < 448 + SPB){
    int s = tid - 448;
    float sg = sigma[b0+s];
    thr_sh[s] = ((sg*sg) * (float)NANT) * L_CONST;
    actsh[s] = 1;
  }
  // one-time md -> LDS (coalesced float4 reads; ordered after md_kernel by stream)
  #pragma unroll
  for (int s = 0; s < SPB; s++){
    float4 v = *(const float4*)(md_ws + (size_t)(b0+s)*DA + (tid<<2));
    md_lds[s][0][tid] = v.x;
    md_lds[s][1][tid] = v.y;
    md_lds[s][2][tid] = v.z;
    md_lds[s][3][tid] = v.w;
  }
  __syncthreads();

  for (int it = 0; it < MAXIT; it++){
    // A: rn2 (tid<4), t = M.residual for active samples (tid 64..319)
    if (tid < SPB){
      float e = 0.f;
      #pragma unroll
      for (int m = 0; m < MM; m++){
        float rr = rsd_re[tid][m], ri = rsd_im[tid][m];
        e += rr*rr + ri*ri;
      }
      rn2_sh[tid] = e;
    } else if (tid >= 64 && tid < 320){
      int q = tid - 64, s = q >> 6, n = q & 63;
      if (actsh[s]){
        float tr = 0.f, ti = 0.f;
        #pragma unroll
        for (int m = 0; m < MM; m++){
          float mr = Msh_re[s][n][m], mi = Msh_im[s][n][m];
          float rr = rsd_re[s][m], ri = rsd_im[s][m];
          tr += mr*rr - mi*ri;
          ti += mr*ri + mi*rr;
        }
        tsh[n][2*s]   = tr;
        tsh[n][2*s+1] = ti;
      }
    }
    __syncthreads();

    bool a0 = actsh[0] && (rn2_sh[0] >= thr_sh[0]);
    bool a1 = actsh[1] && (rn2_sh[1] >= thr_sh[1]);
    bool a2 = actsh[2] && (rn2_sh[2] >= thr_sh[2]);
    bool a3 = actsh[3] && (rn2_sh[3] >= thr_sh[3]);
    if (tid < 4){
      int v = (tid==0) ? (int)a0 : (tid==1) ? (int)a1 : (tid==2) ? (int)a2 : (int)a3;
      actsh[tid] = v;
    }
    if (!(a0 || a1 || a2 || a3)) break;

    // B: g[s][j] = sum_n conj(W[n,a])*t[s,n], a = tid*4+j ; gated per sample
    float gr[SPB][JCOLS], gi[SPB][JCOLS];
    #pragma unroll
    for (int s = 0; s < SPB; s++)
      #pragma unroll
      for (int j = 0; j < JCOLS; j++){ gr[s][j]=0.f; gi[s][j]=0.f; }
    #pragma unroll 8
    for (int n = 0; n < NANT; n++){
      float4 t01 = *(const float4*)&tsh[n][0];
      float4 t23 = *(const float4*)&tsh[n][4];
      float4 wr = *(const float4*)(W_re + (size_t)n*DA + (tid<<2));
      float4 wi = *(const float4*)(W_im + (size_t)n*DA + (tid<<2));
      if (a0){
        gr[0][0] += wr.x*t01.x + wi.x*t01.y;  gi[0][0] += wr.x*t01.y - wi.x*t01.x;
        gr[0][1] += wr.y*t01.x + wi.y*t01.y;  gi[0][1] += wr.y*t01.y - wi.y*t01.x;
        gr[0][2] += wr.z*t01.x + wi.z*t01.y;  gi[0][2] += wr.z*t01.y - wi.z*t01.x;
        gr[0][3] += wr.w*t01.x + wi.w*t01.y;  gi[0][3] += wr.w*t01.y - wi.w*t01.x;
      }
      if (a1){
        gr[1][0] += wr.x*t01.z + wi.x*t01.w;  gi[1][0] += wr.x*t01.w - wi.x*t01.z;
        gr[1][1] += wr.y*t01.z + wi.y*t01.w;  gi[1][1] += wr.y*t01.w - wi.y*t01.z;
        gr[1][2] += wr.z*t01.z + wi.z*t01.w;  gi[1][2] += wr.z*t01.w - wi.z*t01.z;
        gr[1][3] += wr.w*t01.z + wi.w*t01.w;  gi[1][3] += wr.w*t01.w - wi.w*t01.z;
      }
      if (a2){
        gr[2][0] += wr.x*t23.x + wi.x*t23.y;  gi[2][0] += wr.x*t23.y - wi.x*t23.x;
        gr[2][1] += wr.y*t23.x + wi.y*t23.y;  gi[2][1] += wr.y*t23.y - wi.y*t23.x;
        gr[2][2] += wr.z*t23.x + wi.z*t23.y;  gi[2][2] += wr.z*t23.y - wi.z*t23.x;
        gr[2][3] += wr.w*t23.x + wi.w*t23.y;  gi[2][3] += wr.w*t23.y - wi.w*t23.x;
      }
      if (a3){
        gr[3][0] += wr.x*t23.z + wi.x*t23.w;  gi[3][0] += wr.x*t23.w - wi.x*t23.z;
        gr[3][1] += wr.y*t23.z + wi.y*t23.w;  gi[3][1] += wr.y*t23.w - wi.y*t23.z;
        gr[3][2] += wr.z*t23.z + wi.z*t23.w;  gi[3][2] += wr.z*t23.w - wi.z*t23.z;
        gr[3][3] += wr.w*t23.z + wi.w*t23.w;  gi[3][3] += wr.w*t23.w - wi.w*t23.z;
      }
    }

    // C: per-thread best; md from LDS (lane-stride, conflict-free); wave reduce
    const bool acts[4] = {a0, a1, a2, a3};
    float bc2[SPB]; int bix[SPB];
    #pragma unroll
    for (int s = 0; s < SPB; s++){
      bc2[s] = -1.f; bix[s] = 0;
      if (acts[s]){
        float m0 = md_lds[s][0][tid], m1 = md_lds[s][1][tid];
        float m2 = md_lds[s][2][tid], m3 = md_lds[s][3][tid];
        float c0 = (gr[s][0]*gr[s][0] + gi[s][0]*gi[s][0]) * (m0*m0);
        float c1 = (gr[s][1]*gr[s][1] + gi[s][1]*gi[s][1]) * (m1*m1);
        float c2v = (gr[s][2]*gr[s][2] + gi[s][2]*gi[s][2]) * (m2*m2);
        float c3 = (gr[s][3]*gr[s][3] + gi[s][3]*gi[s][3]) * (m3*m3);
        float bc = c0; int bi = (tid<<2);
        if (c1 > bc){ bc = c1; bi = (tid<<2)+1; }
        if (c2v > bc){ bc = c2v; bi = (tid<<2)+2; }
        if (c3 > bc){ bc = c3; bi = (tid<<2)+3; }
        bc2[s] = bc; bix[s] = bi;
      }
    }
    #pragma unroll
    for (int s = 0; s < SPB; s++){
      if (acts[s]){
        #pragma unroll
        for (int off = 32; off; off >>= 1){
          float oc2 = __shfl_down(bc2[s], off);
          int   oix = __shfl_down(bix[s], off);
          if (oc2 > bc2[s] || (oc2 == bc2[s] && oix < bix[s])){ bc2[s]=oc2; bix[s]=oix; }
        }
      }
    }
    if ((tid & 63) == 0){
      int wid = tid >> 6;
      #pragma unroll
      for (int s = 0; s < SPB; s++){
        if (acts[s]){ red_c2[wid][s]=bc2[s]; red_ix[wid][s]=bix[s]; }
      }
    }
    __syncthreads();

    // D1 (wave s, lane=n): cross-wave argmax; val, w2; stage W[:,I] to LDS
    if (tid < 256){
      int s = tid >> 6, lane = tid & 63;
      if (actsh[s]){
        float c = (lane < 16) ? red_c2[lane][s] : -1.f;
        int   bi = (lane < 16) ? red_ix[lane][s] : 0x7FFFFFFF;
        #pragma unroll
        for (int off = 8; off; off >>= 1){
          float oc = __shfl_xor(c, off, 16);
          int   oi = __shfl_xor(bi, off, 16);
          if (oc > c || (oc == c && oi < bi)){ c = oc; bi = oi; }
        }
        int I = __shfl(bi, 0);
        float wr = W_re[(size_t)lane*DA + I], wi = W_im[(size_t)lane*DA + I];
        wselr[s][lane] = wr;
        wseli[s][lane] = wi;
        float tr = tsh[lane][2*s], ti = tsh[lane][2*s+1];
        float vr = wr*tr + wi*ti;
        float vi = wr*ti - wi*tr;
        float w2 = wr*wr + wi*wi;
        #pragma unroll
        for (int off = 32; off; off >>= 1){
          vr += __shfl_xor(vr, off);
          vi += __shfl_xor(vi, off);
          w2 += __shfl_xor(w2, off);
        }
        if (lane == 0){
          float mdv = md_lds[s][I & 3][I >> 2];   // broadcast LDS read
          sel_ix[s] = I;
          sel_vr[s] = vr*mdv;
          sel_vi[s] = vi*mdv;
          sel_md[s] = mdv;
          sel_ei[s] = rsqrtf(w2);
        }
      }
    }
    __syncthreads();

    // D2 (block-parallel): tid<512 -> col[s][m] dots + rsd update;
    //                      512..767 -> res update from staged W
    if (tid < 512){
      int s = tid >> 7, rem = tid & 127, m = rem >> 3, g = rem & 7;
      if (actsh[s]){
        float pr = 0.f, pi = 0.f;
        #pragma unroll
        for (int j = 0; j < 8; j++){
          int n = g*8 + j;
          float mr = Msh_re[s][n][m], mi = Msh_im[s][n][m];
          float wr = wselr[s][n],     wi = wseli[s][n];
          pr += mr*wr + mi*wi;
          pi += mr*wi - mi*wr;
        }
        pr += __shfl_xor(pr, 4, 8);  pi += __shfl_xor(pi, 4, 8);
        pr += __shfl_xor(pr, 2, 8);  pi += __shfl_xor(pi, 2, 8);
        pr += __shfl_xor(pr, 1, 8);  pi += __shfl_xor(pi, 1, 8);
        if (g == 0){
          float mdv = sel_md[s], vr = sel_vr[s], vi = sel_vi[s];
          float cr = pr*mdv, ci2 = pi*mdv;
          rsd_re[s][m] -= vr*cr - vi*ci2;
          rsd_im[s][m] -= vr*ci2 + vi*cr;
        }
      }
    } else if (tid < 768){
      int q = tid - 512, s = q >> 6, n = q & 63;
      if (actsh[s]){
        float wr = wselr[s][n], wi = wseli[s][n];
        float ei = sel_ei[s], vr = sel_vr[s], vi = sel_vi[s];
        float er = wr*ei, em = wi*ei;
        resh_re[s][n] -= vr*er - vi*em;
        resh_im[s][n] -= vr*em + vi*er;
      }
    }
    __syncthreads();
  }

  // ---- epilogue: f32, six planes (re: res,xhat,xhm then im: res,xhat,xhm)
  if (tid < 64){
    int s = tid >> 4, m = tid & 15; int b = b0 + s;
    float rr = rsd_re[s][m], ri = rsd_im[s][m];
    size_t base = (size_t)b*MM + m;
    if (base < outn)          out[base]          = rr;
    if (16384 + base < outn)  out[16384 + base]  = x_re[b*MM+m] - rr;
    if (98304 + base < outn)  out[98304 + base]  = ri;
    if (114688 + base < outn) out[114688 + base] = x_im[b*MM+m] - ri;
  } else if (tid >= 64 && tid < 320){
    int q = tid - 64, s = q >> 6, n = q & 63; int b = b0 + s;
    size_t base = (size_t)b*NANT + n;
    if (32768 + base < outn)  out[32768 + base]  = xm_re[b*NANT+n] - resh_re[s][n];
    if (131072 + base < outn) out[131072 + base] = xm_im[b*NANT+n] - resh_im[s][n];
  }
}

// ================= Fallback: fused single-kernel path ================
__global__ __launch_bounds__(NTHR, 4)
void fused_kernel(const float* __restrict__ x_re, const float* __restrict__ x_im,
                  const float* __restrict__ xm_re, const float* __restrict__ xm_im,
                  const float* __restrict__ M_re, const float* __restrict__ M_im,
                  const float* __restrict__ W_re, const float* __restrict__ W_im,
                  const float* __restrict__ sigma,
                  float* __restrict__ out, int outn_i)
{
  __shared__ float Msh_re[SPB][NANT][MPAD];
  __shared__ float Msh_im[SPB][NANT][MPAD];
  __shared__ float md_T[SPB][JCOLS][NTHR];
  __shared__ float tsh[NANT][8];
  __shared__ float rsd_re[SPB][MM], rsd_im[SPB][MM];
  __shared__ float resh_re[SPB][NANT], resh_im[SPB][NANT];
  __shared__ float red_c2[16][SPB];
  __shared__ int   red_ix[16][SPB];
  __shared__ float rn2_sh[SPB], thr_sh[SPB];
  __shared__ int   actsh[SPB];

  const int tid = threadIdx.x;
  const int b0 = blockIdx.x * SPB;
  const size_t outn = (size_t)outn_i;

  for (int k2 = 0; k2 < 4; k2++){
    int idx = k2*NTHR + tid;
    int s = idx >> 10, rem = idx & 1023;
    int n = rem >> 4, m = rem & 15;
    Msh_re[s][n][m] = M_re[(size_t)b0*1024 + idx];
    Msh_im[s][n][m] = M_im[(size_t)b0*1024 + idx];
  }
  if (tid < SPB*MM){
    int s = tid >> 4, m = tid & 15;
    rsd_re[s][m] = x_re[(b0+s)*MM + m];
    rsd_im[s][m] = x_im[(b0+s)*MM + m];
  } else if (tid >= 64 && tid < 64 + SPB*NANT){
    int q = tid - 64, s = q >> 6, n = q & 63;
    resh_re[s][n] = xm_re[(b0+s)*NANT + n];
    resh_im[s][n] = xm_im[(b0+s)*NANT + n];
  } else if (tid >= 448 && tid < 448 + SPB){
    int s = tid - 448;
    float sg = sigma[b0+s];
    thr_sh[s] = ((sg*sg) * (float)NANT) * L_CONST;
    actsh[s] = 1;
  }

  #pragma unroll
  for (int s = 0; s < SPB; s++){
    const float* MrS = M_re + (size_t)(b0+s)*1024;
    const float* MiS = M_im + (size_t)(b0+s)*1024;
    #pragma unroll
    for (int jc = 0; jc < JCOLS; jc++){
      const int col = (tid<<2) + jc;
      float cr[MM], ci[MM];
      #pragma unroll
      for (int q = 0; q < MM; q++){ cr[q]=0.f; ci[q]=0.f; }
      #pragma unroll 2
      for (int n = 0; n < NANT; n++){
        float wr = W_re[(size_t)n*DA + col];
        float wi = W_im[(size_t)n*DA + col];
        const float* Mr = MrS + n*MM;
        const float* Mi = MiS + n*MM;
        #pragma unroll
        for (int q2 = 0; q2 < 4; q2++){
          float4 m4r = *(const float4*)(Mr + q2*4);
          float4 m4i = *(const float4*)(Mi + q2*4);
          cr[q2*4+0] += m4r.x*wr + m4i.x*wi;  ci[q2*4+0] += m4r.x*wi - m4i.x*wr;
          cr[q2*4+1] += m4r.y*wr + m4i.y*wi;  ci[q2*4+1] += m4r.y*wi - m4i.y*wr;
          cr[q2*4+2] += m4r.z*wr + m4i.z*wi;  ci[q2*4+2] += m4r.z*wi - m4i.z*wr;
          cr[q2*4+3] += m4r.w*wr + m4i.w*wi;  ci[q2*4+3] += m4r.w*wi - m4i.w*wr;
        }
      }
      float nrm = 0.f;
      #pragma unroll
      for (int q = 0; q < MM; q++) nrm += cr[q]*cr[q] + ci[q]*ci[q];
      md_T[s][jc][tid] = 1.f/sqrtf(nrm);
    }
  }
  __syncthreads();

  for (int it = 0; it < MAXIT; it++){
    if (tid < SPB){
      float e = 0.f;
      #pragma unroll
      for (int m = 0; m < MM; m++){
        float rr = rsd_re[tid][m], ri = rsd_im[tid][m];
        e += rr*rr + ri*ri;
      }
      rn2_sh[tid] = e;
    } else if (tid >= 64 && tid < 320){
      int q = tid - 64, s = q >> 6, n = q & 63;
      if (actsh[s]){
        float tr = 0.f, ti = 0.f;
        #pragma unroll
        for (int m = 0; m < MM; m++){
          float mr = Msh_re[s][n][m], mi = Msh_im[s][n][m];
          float rr = rsd_re[s][m], ri = rsd_im[s][m];
          tr += mr*rr - mi*ri;
          ti += mr*ri + mi*rr;
        }
        tsh[n][2*s]   = tr;
        tsh[n][2*s+1] = ti;
      }
    }
    __syncthreads();

    bool a0 = actsh[0] && (rn2_sh[0] >= thr_sh[0]);
    bool a1 = actsh[1] && (rn2_sh[1] >= thr_sh[1]);
    bool a2 = actsh[2] && (rn2_sh[2] >= thr_sh[2]);
    bool a3 = actsh[3] && (rn2_sh[3] >= thr_sh[3]);
    if (tid < 4){
      int v = (tid==0) ? (int)a0 : (tid==1) ? (int)a1 : (tid==2) ? (int)a2 : (int)a3;
      actsh[tid] = v;
    }
    if (!(a0 || a1 || a2 || a3)) break;

    float gr[SPB][JCOLS], gi[SPB][JCOLS];
    #pragma unroll
    for (int s = 0; s < SPB; s++)
      #pragma unroll
      for (int j = 0; j < JCOLS; j++){ gr[s][j]=0.f; gi[s][j]=0.f; }
    #pragma unroll 8
    for (int n = 0; n < NANT; n++){
      float4 t01 = *(const float4*)&tsh[n][0];
      float4 t23 = *(const float4*)&tsh[n][4];
      float4 wr = *(const float4*)(W_re + (size_t)n*DA + (tid<<2));
      float4 wi = *(const float4*)(W_im + (size_t)n*DA + (tid<<2));
      if (a0){
        gr[0][0] += wr.x*t01.x + wi.x*t01.y;  gi[0][0] += wr.x*t01.y - wi.x*t01.x;
        gr[0][1] += wr.y*t01.x + wi.y*t01.y;  gi[0][1] += wr.y*t01.y - wi.y*t01.x;
        gr[0][2] += wr.z*t01.x + wi.z*t01.y;  gi[0][2] += wr.z*t01.y - wi.z*t01.x;
        gr[0][3] += wr.w*t01.x + wi.w*t01.y;  gi[0][3] += wr.w*t01.y - wi.w*t01.x;
      }
      if (a1){
        gr[1][0] += wr.x*t01.z + wi.x*t01.w;  gi[1][0] += wr.x*t01.w - wi.x*t01.z;
        gr[1][1] += wr.y*t01.z + wi.y*t01.w;  gi[1][1] += wr.y*t01.w - wi.y*t01.z;
        gr[1][2] += wr.z*t01.z + wi.z*t01.w;  gi[1][2] += wr.z*t01.w - wi.z*t01.z;
        gr[1][3] += wr.w*t01.z + wi.w*t01.w;  gi[1][3] += wr.w*t01.w - wi.w*t01.z;
      }
      if (a2){
        gr[2][0] += wr.x*t23.x + wi.x*t23.y;  gi[2][0] += wr.x*t23.y - wi.x*t23.x;
        gr[2][1] += wr.y*t23.x + wi.y*t23.y;  gi[2][1] += wr.y*t23.y - wi.y*t23.x;
        gr[2][2] += wr.z*t23.x + wi.z*t23.y;  gi[2][2] += wr.z*t23.y - wi.z*t23.x;
        gr[2][3] += wr.w*t23.x + wi.w*t23.y;  gi[2][3] += wr.w*t23.y - wi.w*t23.x;
      }
      if (a3){
        gr[3][0] += wr.x*t23.z + wi.x*t23.w;  gi[3][0] += wr.x*t23.w - wi.x*t23.z;
        gr[3][1] += wr.y*t23.z + wi.y*t23.w;  gi[3][1] += wr.y*t23.w - wi.y*t23.z;
        gr[3][2] += wr.z*t23.z + wi.z*t23.w;  gi[3][2] += wr.z*t23.w - wi.z*t23.z;
        gr[3][3] += wr.w*t23.z + wi.w*t23.w;  gi[3][3] += wr.w*t23.w - wi.w*t23.z;
      }
    }

    const bool acts[4] = {a0, a1, a2, a3};
    float bc2[SPB]; int bix[SPB];
    #pragma unroll
    for (int s = 0; s < SPB; s++){
      bc2[s] = -1.f; bix[s] = 0;
      if (acts[s]){
        float m0 = md_T[s][0][tid], m1 = md_T[s][1][tid];
        float m2 = md_T[s][2][tid], m3 = md_T[s][3][tid];
        float c0 = (gr[s][0]*gr[s][0] + gi[s][0]*gi[s][0]) * (m0*m0);
        float c1 = (gr[s][1]*gr[s][1] + gi[s][1]*gi[s][1]) * (m1*m1);
        float c2v = (gr[s][2]*gr[s][2] + gi[s][2]*gi[s][2]) * (m2*m2);
        float c3 = (gr[s][3]*gr[s][3] + gi[s][3]*gi[s][3]) * (m3*m3);
        float bc = c0; int bi = (tid<<2);
        if (c1 > bc){ bc = c1; bi = (tid<<2)+1; }
        if (c2v > bc){ bc = c2v; bi = (tid<<2)+2; }
        if (c3 > bc){ bc = c3; bi = (tid<<2)+3; }
        bc2[s] = bc; bix[s] = bi;
      }
    }
    #pragma unroll
    for (int s = 0; s < SPB; s++){
      if (acts[s]){
        #pragma unroll
        for (int off = 32; off; off >>= 1){
          float oc2 = __shfl_down(bc2[s], off);
          int   oix = __shfl_down(bix[s], off);
          if (oc2 > bc2[s] || (oc2 == bc2[s] && oix < bix[s])){ bc2[s]=oc2; bix[s]=oix; }
        }
      }
    }
    if ((tid & 63) == 0){
      int wid = tid >> 6;
      #pragma unroll
      for (int s = 0; s < SPB; s++){
        if (acts[s]){ red_c2[wid][s]=bc2[s]; red_ix[wid][s]=bix[s]; }
      }
    }
    __syncthreads();

    if (tid < 256){
      int s = tid >> 6, lane = tid & 63;
      if (actsh[s]){
        float c = (lane < 16) ? red_c2[lane][s] : -1.f;
        int   bi = (lane < 16) ? red_ix[lane][s] : 0x7FFFFFFF;
        #pragma unroll
        for (int off = 8; off; off >>= 1){
          float oc = __shfl_xor(c, off);
          int   oi = __shfl_xor(bi, off);
          if (oc > c || (oc == c && oi < bi)){ c = oc; bi = oi; }
        }
        int I = __shfl(bi, 0);
        float wr = W_re[(size_t)lane*DA + I], wi = W_im[(size_t)lane*DA + I];
        float tr = tsh[lane][2*s], ti = tsh[lane][2*s+1];
        float vr = wr*tr + wi*ti;
        float vi = wr*ti - wi*tr;
        float w2 = wr*wr + wi*wi;
        #pragma unroll
        for (int off = 32; off; off >>= 1){
          vr += __shfl_xor(vr, off);
          vi += __shfl_xor(vi, off);
          w2 += __shfl_xor(w2, off);
        }
        float mdv = md_T[s][I & 3][I >> 2];
        float val_r = vr*mdv, val_i = vi*mdv;
        float einv = rsqrtf(w2);
        float er = wr*einv, em = wi*einv;
        resh_re[s][lane] -= val_r*er - val_i*em;
        resh_im[s][lane] -= val_r*em + val_i*er;
        for (int m = 0; m < MM; m++){
          float mr = Msh_re[s][lane][m], mi = Msh_im[s][lane][m];
          float pr = mr*wr + mi*wi;
          float pi = mr*wi - mi*wr;
          #pragma unroll
          for (int off = 32; off; off >>= 1){
            pr += __shfl_xor(pr, off);
            pi += __shfl_xor(pi, off);
          }
          if (lane == m){
            float col_r = pr*mdv, col_i = pi*mdv;
            rsd_re[s][m] -= val_r*col_r - val_i*col_i;
            rsd_im[s][m] -= val_r*col_i + val_i*col_r;
          }
        }
      }
    }
    __syncthreads();
  }

  if (tid < 64){
    int s = tid >> 4, m = tid & 15; int b = b0 + s;
    float rr = rsd_re[s][m], ri = rsd_im[s][m];
    size_t base = (size_t)b*MM + m;
    if (base < outn)          out[base]          = rr;
    if (16384 + base < outn)  out[16384 + base]  = x_re[b*MM+m] - rr;
    if (98304 + base < outn)  out[98304 + base]  = ri;
    if (114688 + base < outn) out[114688 + base] = x_im[b*MM+m] - ri;
  } else if (tid >= 64 && tid < 320){
    int q = tid - 64, s = q >> 6, n = q & 63; int b = b0 + s;
    size_t base = (size_t)b*NANT + n;
    if (32768 + base < outn)  out[32768 + base]  = xm_re[b*NANT+n] - resh_re[s][n];
    if (131072 + base < outn) out[131072 + base] = xm_im[b*NANT+n] - resh_im[s][n];
  }
}

extern "C" void kernel_launch(void* const* d_in, const int* in_sizes, int n_in,
                              void* d_out, int out_size, void* d_ws, size_t ws_size,
                              hipStream_t stream) {
  (void)in_sizes; (void)n_in;
  const float* x_re  = (const float*)d_in[0];
  const float* x_im  = (const float*)d_in[1];
  const float* xm_re = (const float*)d_in[2];
  const float* xm_im = (const float*)d_in[3];
  const float* M_re  = (const float*)d_in[4];
  const float* M_im  = (const float*)d_in[5];
  const float* W_re  = (const float*)d_in[6];
  const float* W_im  = (const float*)d_in[7];
  const float* sig   = (const float*)d_in[8];
  float* out = (float*)d_out;

  if (ws_size >= MD_BYTES && d_ws != nullptr){
    float* md_ws = (float*)d_ws;
    hipLaunchKernelGGL(md_kernel, dim3(2048), dim3(256), 0, stream,
                       M_re, M_im, W_re, W_im, md_ws);
    hipLaunchKernelGGL(loop_kernel, dim3(NB_TOT / SPB), dim3(NTHR), 0, stream,
                       x_re, x_im, xm_re, xm_im, M_re, M_im, W_re, W_im,
                       sig, md_ws, out, out_size);
  } else {
    hipLaunchKernelGGL(fused_kernel, dim3(NB_TOT / SPB), dim3(NTHR), 0, stream,
                       x_re, x_im, xm_re, xm_im, M_re, M_im, W_re, W_im,
                       sig, out, out_size);
  }
}